// Round 1
// baseline (455.131 us; speedup 1.0000x reference)
//
#include <hip/hip_runtime.h>
#include <math.h>

#define NB    16
#define CIN   64
#define COUT  64
#define NN    16384
#define HH    8192
#define MODES 2048
#define TEMBD 512

__device__ __forceinline__ int rev13(int x) { return (int)(__brev((unsigned)x) >> 19); }

__global__ void init_tw_k(float2* __restrict__ tw8, float2* __restrict__ tw16) {
  int j = blockIdx.x * blockDim.x + threadIdx.x;
  if (j < 4096) {
    double a = (2.0 * 3.14159265358979323846 / 8192.0) * (double)j;
    tw8[j] = make_float2((float)cos(a), (float)sin(a));
  }
  if (j < 2048) {
    double a = (2.0 * 3.14159265358979323846 / 16384.0) * (double)j;
    tw16[j] = make_float2((float)cos(a), (float)sin(a));
  }
}

// Forward: one block per (b, c_in) row. Pack-trick rfft via 8192-pt complex DIF FFT
// in LDS (output bit-reversed), unpack bins 0..2047, add fused temb scalar.
__global__ __launch_bounds__(256) void fwd_fft_k(
    const float* __restrict__ x, const float* __restrict__ temb,
    const float* __restrict__ dw, const float* __restrict__ db,
    const float2* __restrict__ tw8, const float2* __restrict__ tw16,
    float2* __restrict__ xm)
{
  __shared__ float re[HH];
  __shared__ float im[HH];
  const int row = blockIdx.x;          // b*64 + ci
  const int b = row >> 6, ci = row & 63;
  const int tid = threadIdx.x;

  // t = silu(temb[b]) . dw[ci] + db[ci]  (block-cooperative 512-dot)
  float part = 0.f;
  {
    const float* tb = temb + b * TEMBD;
    const float* wrow = dw + ci * TEMBD;
    for (int j = tid; j < TEMBD; j += 256) {
      float v = tb[j];
      float sg = 1.f / (1.f + __expf(-v));
      part += v * sg * wrow[j];
    }
    for (int off = 32; off > 0; off >>= 1) part += __shfl_down(part, off, 64);
    if ((tid & 63) == 0) re[tid >> 6] = part;
  }
  __syncthreads();
  const float tval = re[0] + re[1] + re[2] + re[3] + db[ci];
  __syncthreads();

  // load row as packed complex z[m] = x[2m] + i x[2m+1]
  const float2* xr = (const float2*)(x + (size_t)row * NN);
  for (int m = tid; m < HH; m += 256) {
    float2 v = xr[m];
    re[m] = v.x; im[m] = v.y;
  }
  __syncthreads();

  // DIF FFT (e^{-i}), natural input -> bit-reversed output
  for (int lh = 12; lh >= 0; --lh) {
    const int h = 1 << lh;
    for (int idx = tid; idx < 4096; idx += 256) {
      const int p = idx & (h - 1);
      const int i0 = ((idx >> lh) << (lh + 1)) + p;
      const int i1 = i0 + h;
      float ur = re[i0], ui = im[i0];
      float vr = re[i1], vi = im[i1];
      float2 w = tw8[p << (12 - lh)];          // (cos, sin); use conj for forward
      float br = ur - vr, bi = ui - vi;
      re[i0] = ur + vr; im[i0] = ui + vi;
      re[i1] = br * w.x + bi * w.y;            // (br+i bi)*(c - i s)
      im[i1] = bi * w.x - br * w.y;
    }
    __syncthreads();
  }

  // unpack X[k] = 0.5(A+conj(B)) - 0.5 i e^{-2pi i k/N} (A-conj(B)),  A=Zf[k], B=Zf[H-k]
  float2* xrow = xm + (size_t)row * MODES;
  for (int k = tid; k < MODES; k += 256) {
    const int ka = rev13(k);
    const int kb = rev13((HH - k) & (HH - 1));
    float Ar = re[ka], Ai = im[ka];
    float Br = re[kb], Bi = -im[kb];
    float Sr = 0.5f * (Ar + Br), Si = 0.5f * (Ai + Bi);
    float Dr = 0.5f * (Ar - Br), Di = 0.5f * (Ai - Bi);
    float2 wv = tw16[k];
    float c = wv.x, s = wv.y;
    float Xr = Sr - s * Dr + c * Di;
    float Xi = Si - s * Di - c * Dr;
    xrow[k] = make_float2(Xr + tval, Xi);
  }
}

// out_m[b,o,m] = sum_i xm[b,i,m] * (wr[i,o,m] + i wi[i,o,m])
// thread = (mode, o); 16 b-accumulators in registers; w read once from HBM.
__global__ __launch_bounds__(256) void spec_mul_k(
    const float2* __restrict__ xm, const float* __restrict__ wr,
    const float* __restrict__ wi, float2* __restrict__ om)
{
  const int m = blockIdx.x * 64 + (threadIdx.x & 63);
  const int o = blockIdx.y * 4 + (threadIdx.x >> 6);
  float2 acc[NB];
#pragma unroll
  for (int b = 0; b < NB; ++b) acc[b] = make_float2(0.f, 0.f);
  for (int i = 0; i < CIN; ++i) {
    const size_t widx = ((size_t)(i * COUT + o)) * MODES + m;
    const float wrv = wr[widx];
    const float wiv = wi[widx];
#pragma unroll
    for (int b = 0; b < NB; ++b) {
      float2 xv = xm[((size_t)(b * CIN + i)) * MODES + m];
      acc[b].x += xv.x * wrv - xv.y * wiv;
      acc[b].y += xv.x * wiv + xv.y * wrv;
    }
  }
#pragma unroll
  for (int b = 0; b < NB; ++b) om[((size_t)(b * COUT + o)) * MODES + m] = acc[b];
}

// Inverse: one block per (b, c_out) row. Build packed half-spectrum Zb (only
// 4096 nonzero bins; Im of bin 0 ignored per numpy irfft), 8192-pt DIT IFFT
// (bit-reversed input -> natural output), write x[2m],x[2m+1] as float2.
__global__ __launch_bounds__(256) void inv_fft_k(
    const float2* __restrict__ om, const float2* __restrict__ tw8,
    const float2* __restrict__ tw16, float* __restrict__ out)
{
  __shared__ float re[HH];
  __shared__ float im[HH];
  const int row = blockIdx.x;   // b*64 + o
  const int tid = threadIdx.x;

  for (int q = tid; q < HH; q += 256) { re[q] = 0.f; im[q] = 0.f; }
  __syncthreads();

  const float2* grow = om + (size_t)row * MODES;
  for (int k = tid; k < MODES; k += 256) {
    float2 g = grow[k];
    if (k == 0) {
      float v = 0.5f * g.x;        // Zb[0] = 0.5*Re(G0)*(1+i)
      re[0] = v; im[0] = v;
    } else {
      // P = 0.5 G[k]; s = i w P, w = e^{+2pi i k/N}; Zb[k]=P+s at rev(k),
      // Zb[H-k]=conj(P-s) at rev(H-k)
      float2 wv = tw16[k];
      float Pr = 0.5f * g.x, Pi = 0.5f * g.y;
      float c = wv.x, s = wv.y;
      float sr = -(c * Pi + s * Pr);
      float si =  (c * Pr - s * Pi);
      int ka = rev13(k);
      int kb = rev13(HH - k);
      re[ka] = Pr + sr; im[ka] = Pi + si;
      re[kb] = Pr - sr; im[kb] = -(Pi - si);
    }
  }
  __syncthreads();

  // DIT IFFT (e^{+i}), bit-reversed input -> natural output
  for (int lh = 0; lh <= 12; ++lh) {
    const int h = 1 << lh;
    for (int idx = tid; idx < 4096; idx += 256) {
      const int p = idx & (h - 1);
      const int i0 = ((idx >> lh) << (lh + 1)) + p;
      const int i1 = i0 + h;
      float2 w = tw8[p << (12 - lh)];
      float vr = re[i1], vi = im[i1];
      float tr = vr * w.x - vi * w.y;          // (vr+i vi)*(c + i s)
      float ti = vr * w.y + vi * w.x;
      float ur = re[i0], ui = im[i0];
      re[i0] = ur + tr; im[i0] = ui + ti;
      re[i1] = ur - tr; im[i1] = ui - ti;
    }
    __syncthreads();
  }

  float2* orow = (float2*)(out + (size_t)row * NN);
  const float sc = 1.0f / 8192.0f;
  for (int m = tid; m < HH; m += 256) {
    orow[m] = make_float2(re[m] * sc, im[m] * sc);
  }
}

extern "C" void kernel_launch(void* const* d_in, const int* in_sizes, int n_in,
                              void* d_out, int out_size, void* d_ws, size_t ws_size,
                              hipStream_t stream) {
  const float* x    = (const float*)d_in[0];
  const float* temb = (const float*)d_in[1];
  const float* wr   = (const float*)d_in[2];
  const float* wi   = (const float*)d_in[3];
  const float* dw   = (const float*)d_in[4];
  const float* db   = (const float*)d_in[5];
  float* out = (float*)d_out;

  char* ws = (char*)d_ws;
  float2* tw8  = (float2*)ws;                               // 32 KiB
  float2* tw16 = (float2*)(ws + 32768);                     // 16 KiB
  float2* xm   = (float2*)(ws + 65536);                     // 16 MiB
  float2* om   = (float2*)(ws + 65536 + (size_t)16777216);  // 16 MiB

  hipLaunchKernelGGL(init_tw_k, dim3(16), dim3(256), 0, stream, tw8, tw16);
  hipLaunchKernelGGL(fwd_fft_k, dim3(NB * CIN), dim3(256), 0, stream,
                     x, temb, dw, db, tw8, tw16, xm);
  hipLaunchKernelGGL(spec_mul_k, dim3(MODES / 64, COUT / 4), dim3(256), 0, stream,
                     xm, wr, wi, om);
  hipLaunchKernelGGL(inv_fft_k, dim3(NB * COUT), dim3(256), 0, stream,
                     om, tw8, tw16, out);
}

// Round 2
// 312.865 us; speedup vs baseline: 1.4547x; 1.4547x over previous
//
#include <hip/hip_runtime.h>
#include <math.h>

#define NB    16
#define CIN   64
#define COUT  64
#define NN    16384
#define HH    8192
#define MODES 2048
#define TEMBD 512

// XOR bank swizzle: bijection on [0,8192); makes stride-32 and contiguous-32
// per-thread LDS access patterns conflict-free without padding (LDS stays 64 KiB).
__device__ __forceinline__ int swz(int e) { return e ^ ((e >> 5) & 31); }
__device__ __forceinline__ int rev13(int x) { return (int)(__brev((unsigned)x) >> 19); }

__global__ void init_tw_k(float2* __restrict__ tw8, float2* __restrict__ tw16) {
  int j = blockIdx.x * blockDim.x + threadIdx.x;
  if (j < 4096) {
    double a = (2.0 * 3.14159265358979323846 / 8192.0) * (double)j;
    tw8[j] = make_float2((float)cos(a), (float)sin(a));
  }
  if (j < 2048) {
    double a = (2.0 * 3.14159265358979323846 / 16384.0) * (double)j;
    tw16[j] = make_float2((float)cos(a), (float)sin(a));
  }
}

// In-register DIF pass: elements e_j = base + j*S (j=0..J-1), stages lh = LH_HI
// down; pbase = base mod h (constant across the pass's stages by construction).
// Twiddle: e^{-2pi i p/8192} = conj(tw8[p<<(12-lh)]), p = pbase + q*S.
template<int J, int S, int LH_HI>
__device__ __forceinline__ void pass_dif(float* zr, float* zi, int pbase,
                                         const float2* __restrict__ tw) {
  int lh = LH_HI;
#pragma unroll
  for (int half = J / 2; half >= 1; half >>= 1, --lh) {
#pragma unroll
    for (int blk = 0; blk < J; blk += 2 * half) {
#pragma unroll
      for (int q = 0; q < half; ++q) {
        const int j0 = blk + q, j1 = j0 + half;
        const float2 w = tw[(pbase + q * S) << (12 - lh)];
        const float ur = zr[j0], ui = zi[j0];
        const float vr = zr[j1], vi = zi[j1];
        zr[j0] = ur + vr; zi[j0] = ui + vi;
        const float br = ur - vr, bi = ui - vi;
        zr[j1] = br * w.x + bi * w.y;   // *(c - i s)
        zi[j1] = bi * w.x - br * w.y;
      }
    }
  }
}

// In-register DIT pass (e^{+i}): stages lh = LH_LO up.
template<int J, int S, int LH_LO>
__device__ __forceinline__ void pass_dit(float* zr, float* zi, int pbase,
                                         const float2* __restrict__ tw) {
  int lh = LH_LO;
#pragma unroll
  for (int half = 1; half <= J / 2; half <<= 1, ++lh) {
#pragma unroll
    for (int blk = 0; blk < J; blk += 2 * half) {
#pragma unroll
      for (int q = 0; q < half; ++q) {
        const int j0 = blk + q, j1 = j0 + half;
        const float2 w = tw[(pbase + q * S) << (12 - lh)];
        const float vr = zr[j1], vi = zi[j1];
        const float tr = vr * w.x - vi * w.y;  // *(c + i s)
        const float ti = vr * w.y + vi * w.x;
        const float ur = zr[j0], ui = zi[j0];
        zr[j0] = ur + tr; zi[j0] = ui + ti;
        zr[j1] = ur - tr; zi[j1] = ui - ti;
      }
    }
  }
}

// Forward: one block per (b, c_in) row. Pack-trick rfft via 8192-pt complex DIF
// FFT: 3 register passes (4+4+5 stages), 3 LDS round-trips. Fused temb scalar.
__global__ __launch_bounds__(256) void fwd_fft_k(
    const float* __restrict__ x, const float* __restrict__ temb,
    const float* __restrict__ dw, const float* __restrict__ db,
    const float2* __restrict__ tw8, const float2* __restrict__ tw16,
    float2* __restrict__ xm)
{
  __shared__ float re[HH];
  __shared__ float im[HH];
  const int row = blockIdx.x;          // b*64 + ci
  const int b = row >> 6, ci = row & 63;
  const int tid = threadIdx.x;

  // t = silu(temb[b]) . dw[ci] + db[ci]  (block-cooperative 512-dot)
  float part = 0.f;
  {
    const float* tb = temb + b * TEMBD;
    const float* wrow = dw + ci * TEMBD;
    for (int j = tid; j < TEMBD; j += 256) {
      float v = tb[j];
      part += v * wrow[j] / (1.f + __expf(-v));
    }
    for (int off = 32; off > 0; off >>= 1) part += __shfl_down(part, off, 64);
    if ((tid & 63) == 0) re[tid >> 6] = part;
  }
  __syncthreads();
  const float tval = re[0] + re[1] + re[2] + re[3] + db[ci];
  __syncthreads();

  float zr[32], zi[32];

  // P1: global (packed z[m] = x[2m] + i x[2m+1]) -> regs, stages lh=12..9, -> LDS
  const float2* xr = (const float2*)(x + (size_t)row * NN);
#pragma unroll
  for (int g = 0; g < 2; ++g) {
    const int i0 = tid + g * 256;
#pragma unroll
    for (int j = 0; j < 16; ++j) {
      float2 v = xr[i0 + j * 512];
      zr[g * 16 + j] = v.x; zi[g * 16 + j] = v.y;
    }
  }
#pragma unroll
  for (int g = 0; g < 2; ++g) {
    const int i0 = tid + g * 256;
    pass_dif<16, 512, 12>(zr + g * 16, zi + g * 16, i0, tw8);
#pragma unroll
    for (int j = 0; j < 16; ++j) {
      const int e = swz(i0 + j * 512);
      re[e] = zr[g * 16 + j]; im[e] = zi[g * 16 + j];
    }
  }
  __syncthreads();

  // P2: stride-32 groups, stages lh=8..5
  {
    const int r = tid & 31;
#pragma unroll
    for (int g = 0; g < 2; ++g) {
      const int base = ((tid >> 5) + g * 8) * 512 + r;
#pragma unroll
      for (int j = 0; j < 16; ++j) {
        const int e = swz(base + j * 32);
        zr[g * 16 + j] = re[e]; zi[g * 16 + j] = im[e];
      }
      pass_dif<16, 32, 8>(zr + g * 16, zi + g * 16, r, tw8);
#pragma unroll
      for (int j = 0; j < 16; ++j) {
        const int e = swz(base + j * 32);
        re[e] = zr[g * 16 + j]; im[e] = zi[g * 16 + j];
      }
    }
  }
  __syncthreads();

  // P3: contiguous-32 groups, stages lh=4..0
  {
    const int base = tid * 32;
#pragma unroll
    for (int j = 0; j < 32; ++j) {
      const int e = swz(base + j);
      zr[j] = re[e]; zi[j] = im[e];
    }
    pass_dif<32, 1, 4>(zr, zi, 0, tw8);
#pragma unroll
    for (int j = 0; j < 32; ++j) {
      const int e = swz(base + j);
      re[e] = zr[j]; im[e] = zi[j];
    }
  }
  __syncthreads();

  // unpack X[k] = 0.5(A+conj(B)) - 0.5 i e^{-2pi i k/N} (A-conj(B)); A=Zf[k], B=Zf[H-k]
  float2* xrow = xm + (size_t)row * MODES;
  for (int k = tid; k < MODES; k += 256) {
    const int ka = swz(rev13(k));
    const int kb = swz(rev13((HH - k) & (HH - 1)));
    float Ar = re[ka], Ai = im[ka];
    float Br = re[kb], Bi = -im[kb];
    float Sr = 0.5f * (Ar + Br), Si = 0.5f * (Ai + Bi);
    float Dr = 0.5f * (Ar - Br), Di = 0.5f * (Ai - Bi);
    float2 wv = tw16[k];
    float c = wv.x, s = wv.y;
    float Xr = Sr - s * Dr + c * Di;
    float Xi = Si - s * Di - c * Dr;
    xrow[k] = make_float2(Xr + tval, Xi);
  }
}

// out_m[b,o,m] = sum_i xm[b,i,m] * (wr[i,o,m] + i wi[i,o,m])
__global__ __launch_bounds__(256) void spec_mul_k(
    const float2* __restrict__ xm, const float* __restrict__ wr,
    const float* __restrict__ wi, float2* __restrict__ om)
{
  const int m = blockIdx.x * 64 + (threadIdx.x & 63);
  const int o = blockIdx.y * 4 + (threadIdx.x >> 6);
  float2 acc[NB];
#pragma unroll
  for (int b = 0; b < NB; ++b) acc[b] = make_float2(0.f, 0.f);
  for (int i = 0; i < CIN; ++i) {
    const size_t widx = ((size_t)(i * COUT + o)) * MODES + m;
    const float wrv = wr[widx];
    const float wiv = wi[widx];
#pragma unroll
    for (int b = 0; b < NB; ++b) {
      float2 xv = xm[((size_t)(b * CIN + i)) * MODES + m];
      acc[b].x += xv.x * wrv - xv.y * wiv;
      acc[b].y += xv.x * wiv + xv.y * wrv;
    }
  }
#pragma unroll
  for (int b = 0; b < NB; ++b) om[((size_t)(b * COUT + o)) * MODES + m] = acc[b];
}

// Inverse: one block per (b, c_out) row. Packed half-spectrum scatter (bit-rev
// positions), then 3 register DIT passes; pass 3 stores straight to global.
__global__ __launch_bounds__(256) void inv_fft_k(
    const float2* __restrict__ om, const float2* __restrict__ tw8,
    const float2* __restrict__ tw16, float* __restrict__ out)
{
  __shared__ float re[HH];
  __shared__ float im[HH];
  const int row = blockIdx.x;   // b*64 + o
  const int tid = threadIdx.x;

  for (int q = tid; q < HH; q += 256) { re[q] = 0.f; im[q] = 0.f; }
  __syncthreads();

  const float2* grow = om + (size_t)row * MODES;
  for (int k = tid; k < MODES; k += 256) {
    float2 g = grow[k];
    if (k == 0) {
      float v = 0.5f * g.x;        // Zb[0] = 0.5*Re(G0)*(1+i)
      re[0] = v; im[0] = v;
    } else {
      // P = 0.5 G[k]; s = i w P, w = e^{+2pi i k/N}; Zb[k]=P+s, Zb[H-k]=conj(P-s)
      float2 wv = tw16[k];
      float Pr = 0.5f * g.x, Pi = 0.5f * g.y;
      float c = wv.x, s = wv.y;
      float sr = -(c * Pi + s * Pr);
      float si =  (c * Pr - s * Pi);
      int ka = swz(rev13(k));
      int kb = swz(rev13(HH - k));
      re[ka] = Pr + sr; im[ka] = Pi + si;
      re[kb] = Pr - sr; im[kb] = -(Pi - si);
    }
  }
  __syncthreads();

  float zr[32], zi[32];

  // P1: contiguous-32 groups, stages lh=0..4
  {
    const int base = tid * 32;
#pragma unroll
    for (int j = 0; j < 32; ++j) {
      const int e = swz(base + j);
      zr[j] = re[e]; zi[j] = im[e];
    }
    pass_dit<32, 1, 0>(zr, zi, 0, tw8);
#pragma unroll
    for (int j = 0; j < 32; ++j) {
      const int e = swz(base + j);
      re[e] = zr[j]; im[e] = zi[j];
    }
  }
  __syncthreads();

  // P2: stride-32 groups, stages lh=5..8
  {
    const int r = tid & 31;
#pragma unroll
    for (int g = 0; g < 2; ++g) {
      const int base = ((tid >> 5) + g * 8) * 512 + r;
#pragma unroll
      for (int j = 0; j < 16; ++j) {
        const int e = swz(base + j * 32);
        zr[g * 16 + j] = re[e]; zi[g * 16 + j] = im[e];
      }
      pass_dit<16, 32, 5>(zr + g * 16, zi + g * 16, r, tw8);
#pragma unroll
      for (int j = 0; j < 16; ++j) {
        const int e = swz(base + j * 32);
        re[e] = zr[g * 16 + j]; im[e] = zi[g * 16 + j];
      }
    }
  }
  __syncthreads();

  // P3: stride-512 groups, stages lh=9..12; write x[2m],x[2m+1] as float2
  {
    float2* orow = (float2*)(out + (size_t)row * NN);
    const float sc = 1.0f / 8192.0f;
#pragma unroll
    for (int g = 0; g < 2; ++g) {
      const int i0 = tid + g * 256;
#pragma unroll
      for (int j = 0; j < 16; ++j) {
        const int e = swz(i0 + j * 512);
        zr[g * 16 + j] = re[e]; zi[g * 16 + j] = im[e];
      }
      pass_dit<16, 512, 9>(zr + g * 16, zi + g * 16, i0, tw8);
#pragma unroll
      for (int j = 0; j < 16; ++j) {
        orow[i0 + j * 512] = make_float2(zr[g * 16 + j] * sc, zi[g * 16 + j] * sc);
      }
    }
  }
}

extern "C" void kernel_launch(void* const* d_in, const int* in_sizes, int n_in,
                              void* d_out, int out_size, void* d_ws, size_t ws_size,
                              hipStream_t stream) {
  const float* x    = (const float*)d_in[0];
  const float* temb = (const float*)d_in[1];
  const float* wr   = (const float*)d_in[2];
  const float* wi   = (const float*)d_in[3];
  const float* dw   = (const float*)d_in[4];
  const float* db   = (const float*)d_in[5];
  float* out = (float*)d_out;

  char* ws = (char*)d_ws;
  float2* tw8  = (float2*)ws;                               // 32 KiB
  float2* tw16 = (float2*)(ws + 32768);                     // 16 KiB
  float2* xm   = (float2*)(ws + 65536);                     // 16 MiB
  float2* om   = (float2*)(ws + 65536 + (size_t)16777216);  // 16 MiB

  hipLaunchKernelGGL(init_tw_k, dim3(16), dim3(256), 0, stream, tw8, tw16);
  hipLaunchKernelGGL(fwd_fft_k, dim3(NB * CIN), dim3(256), 0, stream,
                     x, temb, dw, db, tw8, tw16, xm);
  hipLaunchKernelGGL(spec_mul_k, dim3(MODES / 64, COUT / 4), dim3(256), 0, stream,
                     xm, wr, wi, om);
  hipLaunchKernelGGL(inv_fft_k, dim3(NB * COUT), dim3(256), 0, stream,
                     om, tw8, tw16, out);
}

// Round 3
// 292.807 us; speedup vs baseline: 1.5544x; 1.0685x over previous
//
#include <hip/hip_runtime.h>
#include <math.h>

#define NB    16
#define CIN   64
#define COUT  64
#define NN    16384
#define HH    8192
#define MODES 2048
#define TEMBD 512

// XOR bank swizzle: bijection on [0,8192); makes stride-32 and contiguous-32
// per-thread LDS access patterns conflict-free without padding (LDS stays 64 KiB).
__device__ __forceinline__ int swz(int e) { return e ^ ((e >> 5) & 31); }
__device__ __forceinline__ int rev13(int x) { return (int)(__brev((unsigned)x) >> 19); }

__global__ void init_tw_k(float2* __restrict__ tw8, float2* __restrict__ tw16) {
  int j = blockIdx.x * blockDim.x + threadIdx.x;
  if (j < 4096) {
    double a = (2.0 * 3.14159265358979323846 / 8192.0) * (double)j;
    tw8[j] = make_float2((float)cos(a), (float)sin(a));
  }
  if (j < 2048) {
    double a = (2.0 * 3.14159265358979323846 / 16384.0) * (double)j;
    tw16[j] = make_float2((float)cos(a), (float)sin(a));
  }
}

// In-register DIF pass: elements e_j = base + j*S (j=0..J-1), stages lh = LH_HI
// down; pbase = base mod h (constant across the pass's stages by construction).
template<int J, int S, int LH_HI>
__device__ __forceinline__ void pass_dif(float* zr, float* zi, int pbase,
                                         const float2* __restrict__ tw) {
  int lh = LH_HI;
#pragma unroll
  for (int half = J / 2; half >= 1; half >>= 1, --lh) {
#pragma unroll
    for (int blk = 0; blk < J; blk += 2 * half) {
#pragma unroll
      for (int q = 0; q < half; ++q) {
        const int j0 = blk + q, j1 = j0 + half;
        const float2 w = tw[(pbase + q * S) << (12 - lh)];
        const float ur = zr[j0], ui = zi[j0];
        const float vr = zr[j1], vi = zi[j1];
        zr[j0] = ur + vr; zi[j0] = ui + vi;
        const float br = ur - vr, bi = ui - vi;
        zr[j1] = br * w.x + bi * w.y;   // *(c - i s)
        zi[j1] = bi * w.x - br * w.y;
      }
    }
  }
}

// In-register DIT pass (e^{+i}): stages lh = LH_LO up.
template<int J, int S, int LH_LO>
__device__ __forceinline__ void pass_dit(float* zr, float* zi, int pbase,
                                         const float2* __restrict__ tw) {
  int lh = LH_LO;
#pragma unroll
  for (int half = 1; half <= J / 2; half <<= 1, ++lh) {
#pragma unroll
    for (int blk = 0; blk < J; blk += 2 * half) {
#pragma unroll
      for (int q = 0; q < half; ++q) {
        const int j0 = blk + q, j1 = j0 + half;
        const float2 w = tw[(pbase + q * S) << (12 - lh)];
        const float vr = zr[j1], vi = zi[j1];
        const float tr = vr * w.x - vi * w.y;  // *(c + i s)
        const float ti = vr * w.y + vi * w.x;
        const float ur = zr[j0], ui = zi[j0];
        zr[j0] = ur + tr; zi[j0] = ui + ti;
        zr[j1] = ur - tr; zi[j1] = ui - ti;
      }
    }
  }
}

// Forward: one block per (b, c_in) row. Pack-trick rfft via 8192-pt complex DIF
// FFT: 3 register passes (4+4+5 stages), 3 LDS round-trips. Fused temb scalar.
__global__ __launch_bounds__(256) void fwd_fft_k(
    const float* __restrict__ x, const float* __restrict__ temb,
    const float* __restrict__ dw, const float* __restrict__ db,
    const float2* __restrict__ tw8, const float2* __restrict__ tw16,
    float2* __restrict__ xm)
{
  __shared__ float re[HH];
  __shared__ float im[HH];
  const int row = blockIdx.x;          // b*64 + ci
  const int b = row >> 6, ci = row & 63;
  const int tid = threadIdx.x;

  // t = silu(temb[b]) . dw[ci] + db[ci]  (block-cooperative 512-dot)
  float part = 0.f;
  {
    const float* tb = temb + b * TEMBD;
    const float* wrow = dw + ci * TEMBD;
    for (int j = tid; j < TEMBD; j += 256) {
      float v = tb[j];
      part += v * wrow[j] / (1.f + __expf(-v));
    }
    for (int off = 32; off > 0; off >>= 1) part += __shfl_down(part, off, 64);
    if ((tid & 63) == 0) re[tid >> 6] = part;
  }
  __syncthreads();
  const float tval = re[0] + re[1] + re[2] + re[3] + db[ci];
  __syncthreads();

  float zr[32], zi[32];

  // P1: global (packed z[m] = x[2m] + i x[2m+1]) -> regs, stages lh=12..9, -> LDS
  const float2* xr = (const float2*)(x + (size_t)row * NN);
#pragma unroll
  for (int g = 0; g < 2; ++g) {
    const int i0 = tid + g * 256;
#pragma unroll
    for (int j = 0; j < 16; ++j) {
      float2 v = xr[i0 + j * 512];
      zr[g * 16 + j] = v.x; zi[g * 16 + j] = v.y;
    }
  }
#pragma unroll
  for (int g = 0; g < 2; ++g) {
    const int i0 = tid + g * 256;
    pass_dif<16, 512, 12>(zr + g * 16, zi + g * 16, i0, tw8);
#pragma unroll
    for (int j = 0; j < 16; ++j) {
      const int e = swz(i0 + j * 512);
      re[e] = zr[g * 16 + j]; im[e] = zi[g * 16 + j];
    }
  }
  __syncthreads();

  // P2: stride-32 groups, stages lh=8..5
  {
    const int r = tid & 31;
#pragma unroll
    for (int g = 0; g < 2; ++g) {
      const int base = ((tid >> 5) + g * 8) * 512 + r;
#pragma unroll
      for (int j = 0; j < 16; ++j) {
        const int e = swz(base + j * 32);
        zr[g * 16 + j] = re[e]; zi[g * 16 + j] = im[e];
      }
      pass_dif<16, 32, 8>(zr + g * 16, zi + g * 16, r, tw8);
#pragma unroll
      for (int j = 0; j < 16; ++j) {
        const int e = swz(base + j * 32);
        re[e] = zr[g * 16 + j]; im[e] = zi[g * 16 + j];
      }
    }
  }
  __syncthreads();

  // P3: contiguous-32 groups, stages lh=4..0
  {
    const int base = tid * 32;
#pragma unroll
    for (int j = 0; j < 32; ++j) {
      const int e = swz(base + j);
      zr[j] = re[e]; zi[j] = im[e];
    }
    pass_dif<32, 1, 4>(zr, zi, 0, tw8);
#pragma unroll
    for (int j = 0; j < 32; ++j) {
      const int e = swz(base + j);
      re[e] = zr[j]; im[e] = zi[j];
    }
  }
  __syncthreads();

  // unpack X[k] = 0.5(A+conj(B)) - 0.5 i e^{-2pi i k/N} (A-conj(B)); A=Zf[k], B=Zf[H-k]
  float2* xrow = xm + (size_t)row * MODES;
  for (int k = tid; k < MODES; k += 256) {
    const int ka = swz(rev13(k));
    const int kb = swz(rev13((HH - k) & (HH - 1)));
    float Ar = re[ka], Ai = im[ka];
    float Br = re[kb], Bi = -im[kb];
    float Sr = 0.5f * (Ar + Br), Si = 0.5f * (Ai + Bi);
    float Dr = 0.5f * (Ar - Br), Di = 0.5f * (Ai - Bi);
    float2 wv = tw16[k];
    float c = wv.x, s = wv.y;
    float Xr = Sr - s * Dr + c * Di;
    float Xi = Si - s * Di - c * Dr;
    xrow[k] = make_float2(Xr + tval, Xi);
  }
}

// out_m[b,o,m] = sum_i xm[b,i,m] * (wr[i,o,m] + i wi[i,o,m])
// thread = (m, o); 4 b-accumulators; grid z splits batch 16 -> 4 chunks so
// 2048 blocks = 8 blocks/CU (full 32-wave occupancy for latency hiding).
__global__ __launch_bounds__(256) void spec_mul_k(
    const float2* __restrict__ xm, const float* __restrict__ wr,
    const float* __restrict__ wi, float2* __restrict__ om)
{
  const int m = blockIdx.x * 64 + (threadIdx.x & 63);
  const int o = blockIdx.y * 4 + (threadIdx.x >> 6);
  const int b0 = blockIdx.z * 4;
  float2 acc[4];
#pragma unroll
  for (int b = 0; b < 4; ++b) acc[b] = make_float2(0.f, 0.f);
  for (int i = 0; i < CIN; ++i) {
    const size_t widx = ((size_t)(i * COUT + o)) * MODES + m;
    const float wrv = wr[widx];
    const float wiv = wi[widx];
#pragma unroll
    for (int b = 0; b < 4; ++b) {
      float2 xv = xm[((size_t)((b0 + b) * CIN + i)) * MODES + m];
      acc[b].x += xv.x * wrv - xv.y * wiv;
      acc[b].y += xv.x * wiv + xv.y * wrv;
    }
  }
#pragma unroll
  for (int b = 0; b < 4; ++b)
    om[((size_t)((b0 + b) * COUT + o)) * MODES + m] = acc[b];
}

// Inverse: one block per (b, c_out) row. Packed half-spectrum scatter (bit-rev
// positions), then 3 register DIT passes; pass 3 stores straight to global.
__global__ __launch_bounds__(256) void inv_fft_k(
    const float2* __restrict__ om, const float2* __restrict__ tw8,
    const float2* __restrict__ tw16, float* __restrict__ out)
{
  __shared__ float re[HH];
  __shared__ float im[HH];
  const int row = blockIdx.x;   // b*64 + o
  const int tid = threadIdx.x;

  for (int q = tid; q < HH; q += 256) { re[q] = 0.f; im[q] = 0.f; }
  __syncthreads();

  const float2* grow = om + (size_t)row * MODES;
  for (int k = tid; k < MODES; k += 256) {
    float2 g = grow[k];
    if (k == 0) {
      float v = 0.5f * g.x;        // Zb[0] = 0.5*Re(G0)*(1+i)
      re[0] = v; im[0] = v;
    } else {
      // P = 0.5 G[k]; s = i w P, w = e^{+2pi i k/N}; Zb[k]=P+s, Zb[H-k]=conj(P-s)
      float2 wv = tw16[k];
      float Pr = 0.5f * g.x, Pi = 0.5f * g.y;
      float c = wv.x, s = wv.y;
      float sr = -(c * Pi + s * Pr);
      float si =  (c * Pr - s * Pi);
      int ka = swz(rev13(k));
      int kb = swz(rev13(HH - k));
      re[ka] = Pr + sr; im[ka] = Pi + si;
      re[kb] = Pr - sr; im[kb] = -(Pi - si);
    }
  }
  __syncthreads();

  float zr[32], zi[32];

  // P1: contiguous-32 groups, stages lh=0..4
  {
    const int base = tid * 32;
#pragma unroll
    for (int j = 0; j < 32; ++j) {
      const int e = swz(base + j);
      zr[j] = re[e]; zi[j] = im[e];
    }
    pass_dit<32, 1, 0>(zr, zi, 0, tw8);
#pragma unroll
    for (int j = 0; j < 32; ++j) {
      const int e = swz(base + j);
      re[e] = zr[j]; im[e] = zi[j];
    }
  }
  __syncthreads();

  // P2: stride-32 groups, stages lh=5..8
  {
    const int r = tid & 31;
#pragma unroll
    for (int g = 0; g < 2; ++g) {
      const int base = ((tid >> 5) + g * 8) * 512 + r;
#pragma unroll
      for (int j = 0; j < 16; ++j) {
        const int e = swz(base + j * 32);
        zr[g * 16 + j] = re[e]; zi[g * 16 + j] = im[e];
      }
      pass_dit<16, 32, 5>(zr + g * 16, zi + g * 16, r, tw8);
#pragma unroll
      for (int j = 0; j < 16; ++j) {
        const int e = swz(base + j * 32);
        re[e] = zr[g * 16 + j]; im[e] = zi[g * 16 + j];
      }
    }
  }
  __syncthreads();

  // P3: stride-512 groups, stages lh=9..12; write x[2m],x[2m+1] as float2
  {
    float2* orow = (float2*)(out + (size_t)row * NN);
    const float sc = 1.0f / 8192.0f;
#pragma unroll
    for (int g = 0; g < 2; ++g) {
      const int i0 = tid + g * 256;
#pragma unroll
      for (int j = 0; j < 16; ++j) {
        const int e = swz(i0 + j * 512);
        zr[g * 16 + j] = re[e]; zi[g * 16 + j] = im[e];
      }
      pass_dit<16, 512, 9>(zr + g * 16, zi + g * 16, i0, tw8);
#pragma unroll
      for (int j = 0; j < 16; ++j) {
        orow[i0 + j * 512] = make_float2(zr[g * 16 + j] * sc, zi[g * 16 + j] * sc);
      }
    }
  }
}

extern "C" void kernel_launch(void* const* d_in, const int* in_sizes, int n_in,
                              void* d_out, int out_size, void* d_ws, size_t ws_size,
                              hipStream_t stream) {
  const float* x    = (const float*)d_in[0];
  const float* temb = (const float*)d_in[1];
  const float* wr   = (const float*)d_in[2];
  const float* wi   = (const float*)d_in[3];
  const float* dw   = (const float*)d_in[4];
  const float* db   = (const float*)d_in[5];
  float* out = (float*)d_out;

  char* ws = (char*)d_ws;
  float2* tw8  = (float2*)ws;                               // 32 KiB
  float2* tw16 = (float2*)(ws + 32768);                     // 16 KiB
  float2* xm   = (float2*)(ws + 65536);                     // 16 MiB
  float2* om   = (float2*)(ws + 65536 + (size_t)16777216);  // 16 MiB

  hipLaunchKernelGGL(init_tw_k, dim3(16), dim3(256), 0, stream, tw8, tw16);
  hipLaunchKernelGGL(fwd_fft_k, dim3(NB * CIN), dim3(256), 0, stream,
                     x, temb, dw, db, tw8, tw16, xm);
  hipLaunchKernelGGL(spec_mul_k, dim3(MODES / 64, COUT / 4, NB / 4), dim3(256), 0, stream,
                     xm, wr, wi, om);
  hipLaunchKernelGGL(inv_fft_k, dim3(NB * COUT), dim3(256), 0, stream,
                     om, tw8, tw16, out);
}